// Round 13
// baseline (3278.704 us; speedup 1.0000x reference)
//
#include <hip/hip_runtime.h>
#include <hip/hip_bf16.h>
#include <stdint.h>

// Problem constants (fixed by the reference)
#define TT 32768   // total tokens
#define DD 2048    // model dim
#define HH 5632    // hidden dim
#define NE 8       // experts

typedef __bf16 bf16;
typedef __bf16 bf16x8 __attribute__((ext_vector_type(8)));
typedef float  f32x4  __attribute__((ext_vector_type(4)));

__device__ __forceinline__ void gl16(const void* g, void* l) {
    __builtin_amdgcn_global_load_lds(
        (const __attribute__((address_space(1))) void*)g,
        (__attribute__((address_space(3))) void*)l, 16, 0, 0);
}
#define VMW(n) asm volatile("s_waitcnt vmcnt(" #n ")" ::: "memory")
#define LGKM0() do { asm volatile("s_waitcnt lgkmcnt(0)" ::: "memory"); \
                     __builtin_amdgcn_sched_barrier(0); } while (0)
#define BARRIER() __builtin_amdgcn_s_barrier()

// LDS XOR-swizzle for 64-B rows: measured 0 bank conflicts (r2-r12).
__device__ __forceinline__ int swz(int off) { return off ^ (((off >> 7) & 3) << 4); }

__device__ __forceinline__ int expert_of(const int* counts, int row0) {
    int base = 0;
    for (int i = 0; i < NE; ++i) { int c = counts[i]; if (row0 < base + c) return i; base += c; }
    return NE - 1;
}

// ---------------- f32 -> bf16 convert (x and w2 only now) ----------------
__global__ __launch_bounds__(256)
void k_cvt(const float* __restrict__ in, bf16* __restrict__ out, long n) {
    long i = ((long)blockIdx.x * 256 + threadIdx.x) * 8;
    const long stride = (long)gridDim.x * 256 * 8;
    for (; i < n; i += stride) {
        const float4* p = (const float4*)(in + i);
        float4 a = p[0], b = p[1];
        union { bf16 v[8]; uint4 u; } r;
        r.v[0] = (bf16)a.x; r.v[1] = (bf16)a.y; r.v[2] = (bf16)a.z; r.v[3] = (bf16)a.w;
        r.v[4] = (bf16)b.x; r.v[5] = (bf16)b.y; r.v[6] = (bf16)b.z; r.v[7] = (bf16)b.w;
        *(uint4*)(out + i) = r.u;
    }
}

// =====================================================================
// r13 moe1: r12 static persistent pipeline + FUSED W1/W3 f32->bf16
// conversion in the B-staging path (w1/w3 cvt kernels deleted).
//   A side  : gl16 bf16 staging, lead 3 (unchanged).
//   B side  : phase A of tile t issues 4 dwordx4 f32 loads for tile t+2
//             into reg set (k&1); end of phase B converts set (k+1)&1 and
//             ds_writes B(t+1) into buf[(t+1)&3] (its B reads ended t-3).
// vmcnt ledger (per wave; issue order per tile: Wf(t+2)[4] then A(t+3)[2]):
//   steady queue before end-of-t drain:
//     A(t+1)2, Wf(t+1)4, A(t+2)2, Wf(t+2)4, A(t+3)2  = 14
//   VMW(8) drains A(t+1) [needed t+1 reads] + Wf(t+1) [written now].
//   write B(t+1) -> lgkmcnt(0) -> barrier orders it before t+1's reads.
//   Final-seg tail: t=61 VMW(6), t=62 VMW(0), t=63 none.
//   Prologue: Wf(0),Wf(1),A(0),A(1),A(2)=14; VMW(10) [drain Wf(0)],
//   write B(0); VMW(4) [drain A(0)]; lgkm; barrier.
// =====================================================================
__global__ __launch_bounds__(512, 2)
void k_moe1(const bf16* __restrict__ xb, const float* __restrict__ w1,
            const float* __restrict__ w3, const int* __restrict__ counts,
            bf16* __restrict__ h) {
    extern __shared__ __align__(16) char sm[];
    const int tid = threadIdx.x;
    const int c = blockIdx.x & 7;      // XCD (round-robin dispatch, 256%8==0)
    const int j = blockIdx.x >> 3;     // [0,32)
    const int NSEG = 22;

    const int mt = (c << 4) + (j & 15);
    const int row0 = mt * 256;
    const int e = expert_of(counts, row0);

    const int s0 = swz(tid * 16);
    const int s1 = 8192 + s0;
    const int dst0 = tid * 16;

    const char* sa0 = (const char*)xb + (((size_t)(row0 + (s0 >> 6)) * DD) << 1) + (s0 & 63);
    const char* sa1 = (const char*)xb + (((size_t)(row0 + (s1 >> 6)) * DD) << 1) + (s1 & 63);

    // f32 weight bases for the B pre-swizzled staging position:
    // bf16 col-byte (s0&63) -> f32 byte (s0&63)*2; row = c0 + (s0>>6).
    int c0 = (j >> 4) * 128;           // seg-0 weight col block (nt = sg*2 + j>>4)
    const char* w1f = (const char*)w1 + (((size_t)e * HH * DD) << 2)
                      + (((size_t)(c0 + (s0 >> 6)) * DD) << 2) + ((s0 & 63) << 1);
    const char* w3f = (const char*)w3 + (((size_t)e * HH * DD) << 2)
                      + (((size_t)(c0 + (s0 >> 6)) * DD) << 2) + ((s0 & 63) << 1);
    const size_t WADVf = ((size_t)256 * DD) << 2;   // nt += 2 per segment (f32)

    auto stageA = [&](int ko, int bufb) {
        gl16(sa0 + ko, sm + bufb + dst0);
        gl16(sa1 + ko, sm + bufb + 8192 + dst0);
    };
    auto wfload = [&](int tau, float4& l1a, float4& l1b, float4& l3a, float4& l3b) {
        const char* p1 = w1f + ((size_t)tau << 7);   // tau*32 f32 = 128 B
        const char* p3 = w3f + ((size_t)tau << 7);
        l1a = *(const float4*)(p1);      l1b = *(const float4*)(p1 + 16);
        l3a = *(const float4*)(p3);      l3b = *(const float4*)(p3 + 16);
    };
    auto wfwrite = [&](int bufb, const float4& l1a, const float4& l1b,
                       const float4& l3a, const float4& l3b) {
        union { bf16 v[8]; uint4 u; } r1, r3;
        r1.v[0] = (bf16)l1a.x; r1.v[1] = (bf16)l1a.y; r1.v[2] = (bf16)l1a.z; r1.v[3] = (bf16)l1a.w;
        r1.v[4] = (bf16)l1b.x; r1.v[5] = (bf16)l1b.y; r1.v[6] = (bf16)l1b.z; r1.v[7] = (bf16)l1b.w;
        r3.v[0] = (bf16)l3a.x; r3.v[1] = (bf16)l3a.y; r3.v[2] = (bf16)l3a.z; r3.v[3] = (bf16)l3a.w;
        r3.v[4] = (bf16)l3b.x; r3.v[5] = (bf16)l3b.y; r3.v[6] = (bf16)l3b.z; r3.v[7] = (bf16)l3b.w;
        *(uint4*)(sm + bufb + 16384 + dst0) = r1.u;
        *(uint4*)(sm + bufb + 24576 + dst0) = r3.u;
    };

    const int lane = tid & 63, wv = tid >> 6;
    const int wrow = wv >> 2, wcol = wv & 3;      // wave = 128 rows x 32 cols/mat
    const int lrow = lane & 15, kb = (lane >> 4) << 4;
    const int aoff0 = swz((wrow * 128 + lrow) * 64 + kb);   // + mi*1024
    const int boff0 = swz((wcol * 32 + lrow) * 64 + kb);    // + ni*1024

    f32x4 acc1[8][2] = {};
    f32x4 acc3[8][2] = {};
    // two Wf register sets (static index via k&1 — rule #20 safe)
    float4 A1a, A1b, A3a, A3b;   // set 0
    float4 B1a, B1b, B3a, B3b;   // set 1

    // ---- prologue ----
    wfload(0, A1a, A1b, A3a, A3b);        // Wf(0) -> set0
    wfload(1, B1a, B1b, B3a, B3b);        // Wf(1) -> set1
    stageA(0, 0); stageA(64, 1 << 15); stageA(128, 2 << 15);
    VMW(10);                               // drain Wf(0)
    __builtin_amdgcn_sched_barrier(0);
    wfwrite(0, A1a, A1b, A3a, A3b);        // B(0) -> buf0
    VMW(4);                                // drain A(0) (Wf(1) drains too; regs)
    LGKM0();
    BARRIER();

    int ccol0 = (j >> 4) * 128;
    const int crow = row0 + wrow * 128 + ((lane >> 4) << 2);

    for (int sg = 0; sg < NSEG; ++sg) {
        const bool fin = (sg == NSEG - 1);
        for (int tp = 0; tp < 16; ++tp) {
#pragma unroll
            for (int k = 0; k < 4; ++k) {
                const int t = tp * 4 + k;
                const char* db = sm + (k << 15);             // compile-time
                const int bS = ((k + 3) & 3) << 15;          // compile-time
                bf16x8 af[4], b1[2], b3[2];
                // ---------------- phase A: mi 0-3 ----------------
#pragma unroll
                for (int mi = 0; mi < 4; ++mi) af[mi] = *(const bf16x8*)(db + aoff0 + mi * 1024);
#pragma unroll
                for (int ni = 0; ni < 2; ++ni) {
                    b1[ni] = *(const bf16x8*)(db + 16384 + boff0 + ni * 1024);
                    b3[ni] = *(const bf16x8*)(db + 24576 + boff0 + ni * 1024);
                }
                if (t == 62 && !fin) { w1f += WADVf; w3f += WADVf; }   // next-seg cols
                if (!fin || t <= 61) {                     // Wf(t+2), set = k&1
                    if ((k & 1) == 0) wfload((t + 2) & 63, A1a, A1b, A3a, A3b);
                    else              wfload((t + 2) & 63, B1a, B1b, B3a, B3b);
                }
                if (!fin || t < 61) stageA(((t + 3) & 63) << 6, bS);
                BARRIER();
                LGKM0();
                __builtin_amdgcn_s_setprio(1);
#pragma unroll
                for (int mi = 0; mi < 4; ++mi)
#pragma unroll
                    for (int ni = 0; ni < 2; ++ni) {
                        acc1[mi][ni] = __builtin_amdgcn_mfma_f32_16x16x32_bf16(af[mi], b1[ni], acc1[mi][ni], 0, 0, 0);
                        acc3[mi][ni] = __builtin_amdgcn_mfma_f32_16x16x32_bf16(af[mi], b3[ni], acc3[mi][ni], 0, 0, 0);
                    }
                __builtin_amdgcn_s_setprio(0);
                BARRIER();
                // ---------------- phase B: mi 4-7 (B frags reused) ----------------
                bf16x8 ag[4];
#pragma unroll
                for (int mi = 0; mi < 4; ++mi) ag[mi] = *(const bf16x8*)(db + aoff0 + (mi + 4) * 1024);
                BARRIER();
                LGKM0();
                __builtin_amdgcn_s_setprio(1);
#pragma unroll
                for (int mi = 0; mi < 4; ++mi)
#pragma unroll
                    for (int ni = 0; ni < 2; ++ni) {
                        acc1[mi + 4][ni] = __builtin_amdgcn_mfma_f32_16x16x32_bf16(ag[mi], b1[ni], acc1[mi + 4][ni], 0, 0, 0);
                        acc3[mi + 4][ni] = __builtin_amdgcn_mfma_f32_16x16x32_bf16(ag[mi], b3[ni], acc3[mi + 4][ni], 0, 0, 0);
                    }
                __builtin_amdgcn_s_setprio(0);
                // ---- end-of-tile drain + deferred B(t+1) write ----
                if (!fin || t < 61) { VMW(8); }
                else if (t == 61)   { VMW(6); }
                else if (t == 62)   { VMW(0); }
                __builtin_amdgcn_sched_barrier(0);
                if (!fin || t < 63) {                      // write B(t+1), set (k+1)&1
                    const int bW = ((k + 1) & 3) << 15;
                    if (((k + 1) & 1) == 0) wfwrite(bW, A1a, A1b, A3a, A3b);
                    else                    wfwrite(bW, B1a, B1b, B3a, B3b);
                    LGKM0();
                }
                BARRIER();
            }
        }
        // segment epilogue: bf16-round h1,h3 (ragged_dot bf16 outs), silu, bf16 h
#pragma unroll
        for (int mi = 0; mi < 8; ++mi)
#pragma unroll
            for (int ni = 0; ni < 2; ++ni) {
#pragma unroll
                for (int jj = 0; jj < 4; ++jj) {
                    int row = crow + mi * 16 + jj;
                    int col = ccol0 + wcol * 32 + ni * 16 + lrow;
                    float f1 = (float)(bf16)acc1[mi][ni][jj];
                    float f3 = (float)(bf16)acc3[mi][ni][jj];
                    float s = f1 / (1.0f + __expf(-f1));
                    h[(size_t)row * HH + col] = (bf16)(s * f3);
                }
                acc1[mi][ni] = (f32x4){0.f, 0.f, 0.f, 0.f};
                acc3[mi][ni] = (f32x4){0.f, 0.f, 0.f, 0.f};
            }
        ccol0 += 256;   // nt += 2
    }
}

// =====================================================================
// r12 g2 (verbatim, proven): persistent, static inner pipeline, bf16 W2.
// =====================================================================
__global__ __launch_bounds__(512, 2)
void k_g2(const bf16* __restrict__ hb, const bf16* __restrict__ w2b,
          const int* __restrict__ counts, float* __restrict__ out) {
    extern __shared__ __align__(16) char sm[];
    const int tid = threadIdx.x;
    const int c = blockIdx.x & 7;
    const int j = blockIdx.x >> 3;     // [0,32)
    const int NSEG = 4;
    const int NT = 176;                // HH/32

    const int mt = (c << 4) + (j & 15);
    const int row0 = mt * 256;
    const int e = expert_of(counts, row0);

    const int s0 = swz(tid * 16);
    const int s1 = 8192 + s0;
    const int dst0 = tid * 16;

    const char* sa0 = (const char*)hb + (((size_t)(row0 + (s0 >> 6)) * HH) << 1) + (s0 & 63);
    const char* sa1 = (const char*)hb + (((size_t)(row0 + (s1 >> 6)) * HH) << 1) + (s1 & 63);
    const char* wp = (const char*)(w2b + (size_t)e * DD * HH);
    int c0 = (j >> 4) * 256;
    const char* sa2 = wp + (((size_t)(c0 + (s0 >> 6)) * HH) << 1) + (s0 & 63);
    const char* sa3 = wp + (((size_t)(c0 + (s1 >> 6)) * HH) << 1) + (s1 & 63);
    const size_t WADV = ((size_t)512 * HH) << 1;

    auto stageA = [&](int ko, int bufb) {
        gl16(sa0 + ko, sm + bufb + dst0);
        gl16(sa1 + ko, sm + bufb + 8192 + dst0);
    };
    auto stageB = [&](int ko, int bufb) {
        gl16(sa2 + ko, sm + bufb + 16384 + dst0);
        gl16(sa3 + ko, sm + bufb + 24576 + dst0);
    };

    const int lane = tid & 63, wv = tid >> 6;
    const int wrow = wv >> 2, wcol = wv & 3;
    const int lrow = lane & 15, kb = (lane >> 4) << 4;
    const int aoff0 = swz((wrow * 128 + lrow) * 64 + kb);
    const int boff0 = swz((wcol * 64 + lrow) * 64 + kb);

    f32x4 acc[8][4] = {};

    stageA(0, 0);          stageB(0, 0);
    stageA(64, 1 << 15);   stageB(64, 1 << 15);
    stageA(128, 2 << 15);  stageB(128, 2 << 15);
    VMW(8);
    BARRIER();

    int ccol0 = (j >> 4) * 256;
    const int crow = row0 + wrow * 128 + ((lane >> 4) << 2);

    for (int sg = 0; sg < NSEG; ++sg) {
        const bool fin = (sg == NSEG - 1);
        for (int tp = 0; tp < 44; ++tp) {
#pragma unroll
            for (int k = 0; k < 4; ++k) {
                const int t = tp * 4 + k;
                const char* db = sm + (k << 15);
                const int bS = ((k + 3) & 3) << 15;
                const int t3 = (t + 3 >= NT) ? t + 3 - NT : t + 3;
                const int ko3 = t3 << 6;
                bf16x8 af[4], bf[4];
#pragma unroll
                for (int mi = 0; mi < 4; ++mi) af[mi] = *(const bf16x8*)(db + aoff0 + mi * 1024);
#pragma unroll
                for (int ni = 0; ni < 4; ++ni) bf[ni] = *(const bf16x8*)(db + 16384 + boff0 + ni * 1024);
                if (t == NT - 3 && !fin) { sa2 += WADV; sa3 += WADV; }
                if (!fin || t < NT - 3) stageA(ko3, bS);
                BARRIER();
                LGKM0();
                __builtin_amdgcn_s_setprio(1);
#pragma unroll
                for (int mi = 0; mi < 4; ++mi)
#pragma unroll
                    for (int ni = 0; ni < 4; ++ni)
                        acc[mi][ni] = __builtin_amdgcn_mfma_f32_16x16x32_bf16(af[mi], bf[ni], acc[mi][ni], 0, 0, 0);
                __builtin_amdgcn_s_setprio(0);
                BARRIER();
                bf16x8 ag[4];
#pragma unroll
                for (int mi = 0; mi < 4; ++mi) ag[mi] = *(const bf16x8*)(db + aoff0 + (mi + 4) * 1024);
                if (!fin || t < NT - 3) { stageB(ko3, bS); VMW(8); }
                else if (t == NT - 3) { VMW(4); }
                else if (t == NT - 2) { VMW(0); }
                BARRIER();
                LGKM0();
                __builtin_amdgcn_s_setprio(1);
#pragma unroll
                for (int mi = 0; mi < 4; ++mi)
#pragma unroll
                    for (int ni = 0; ni < 4; ++ni)
                        acc[mi + 4][ni] = __builtin_amdgcn_mfma_f32_16x16x32_bf16(ag[mi], bf[ni], acc[mi + 4][ni], 0, 0, 0);
                __builtin_amdgcn_s_setprio(0);
                BARRIER();
            }
        }
#pragma unroll
        for (int mi = 0; mi < 8; ++mi)
#pragma unroll
            for (int ni = 0; ni < 4; ++ni) {
#pragma unroll
                for (int jj = 0; jj < 4; ++jj) {
                    int row = crow + mi * 16 + jj;
                    int col = ccol0 + wcol * 64 + ni * 16 + lrow;
                    out[(size_t)row * DD + col] = (float)(bf16)acc[mi][ni][jj];
                }
                acc[mi][ni] = (f32x4){0.f, 0.f, 0.f, 0.f};
            }
        ccol0 += 512;
    }
}

extern "C" void kernel_launch(void* const* d_in, const int* in_sizes, int n_in,
                              void* d_out, int out_size, void* d_ws, size_t ws_size,
                              hipStream_t stream) {
    const float* x      = (const float*)d_in[0];
    const float* w1     = (const float*)d_in[1];
    const float* w2     = (const float*)d_in[2];
    const float* w3     = (const float*)d_in[3];
    const int*   counts = (const int*)d_in[4];
    float* out = (float*)d_out;

    const size_t xb_b = (size_t)TT * DD * 2;        // 128 MiB
    const size_t h_b  = (size_t)TT * HH * 2;        // 352 MiB
    const size_t w_b  = (size_t)NE * HH * DD * 2;   // 176 MiB (w2b only)
    if (ws_size < xb_b + h_b + w_b) return;         // 656 MiB (proven available)

    bf16* xb  = (bf16*)d_ws;
    bf16* h   = (bf16*)((char*)d_ws + xb_b);
    bf16* wsA = (bf16*)((char*)d_ws + xb_b + h_b);

    hipFuncSetAttribute((const void*)k_moe1, hipFuncAttributeMaxDynamicSharedMemorySize, 131072);
    hipFuncSetAttribute((const void*)k_g2,   hipFuncAttributeMaxDynamicSharedMemorySize, 131072);

    k_cvt<<<2048, 256, 0, stream>>>(x,  xb,  (long)TT * DD);
    k_moe1<<<256, 512, 131072, stream>>>(xb, w1, w3, counts, h);
    k_cvt<<<2048, 256, 0, stream>>>(w2, wsA, (long)NE * DD * HH);
    k_g2<<<256, 512, 131072, stream>>>(h, wsA, counts, out);
}

// Round 14
// 2683.178 us; speedup vs baseline: 1.2219x; 1.2219x over previous
//
#include <hip/hip_runtime.h>
#include <hip/hip_bf16.h>
#include <stdint.h>

// Problem constants (fixed by the reference)
#define TT 32768   // total tokens
#define DD 2048    // model dim
#define HH 5632    // hidden dim
#define NE 8       // experts

typedef __bf16 bf16;
typedef __bf16 bf16x8 __attribute__((ext_vector_type(8)));
typedef float  f32x4  __attribute__((ext_vector_type(4)));

__device__ __forceinline__ void gl16(const void* g, void* l) {
    __builtin_amdgcn_global_load_lds(
        (const __attribute__((address_space(1))) void*)g,
        (__attribute__((address_space(3))) void*)l, 16, 0, 0);
}
#define VMW(n) asm volatile("s_waitcnt vmcnt(" #n ")" ::: "memory")
#define LGKM0() do { asm volatile("s_waitcnt lgkmcnt(0)" ::: "memory"); \
                     __builtin_amdgcn_sched_barrier(0); } while (0)
#define BARRIER() __builtin_amdgcn_s_barrier()

// LDS XOR-swizzle for 64-B rows: measured 0 bank conflicts (r2-r12).
__device__ __forceinline__ int swz(int off) { return off ^ (((off >> 7) & 3) << 4); }

__device__ __forceinline__ int expert_of(const int* counts, int row0) {
    int base = 0;
    for (int i = 0; i < NE; ++i) { int c = counts[i]; if (row0 < base + c) return i; base += c; }
    return NE - 1;
}

// ---------------- f32 -> bf16 convert ----------------
__global__ __launch_bounds__(256)
void k_cvt(const float* __restrict__ in, bf16* __restrict__ out, long n) {
    long i = ((long)blockIdx.x * 256 + threadIdx.x) * 8;
    const long stride = (long)gridDim.x * 256 * 8;
    for (; i < n; i += stride) {
        const float4* p = (const float4*)(in + i);
        float4 a = p[0], b = p[1];
        union { bf16 v[8]; uint4 u; } r;
        r.v[0] = (bf16)a.x; r.v[1] = (bf16)a.y; r.v[2] = (bf16)a.z; r.v[3] = (bf16)a.w;
        r.v[4] = (bf16)b.x; r.v[5] = (bf16)b.y; r.v[6] = (bf16)b.z; r.v[7] = (bf16)b.w;
        *(uint4*)(out + i) = r.u;
    }
}

// =====================================================================
// r14 moe1: 2-blocks-per-CU co-residency, tile kept at 256x128(x2 mats).
// LDS = 2 buffers x 32 KiB = 64 KiB -> 2 blocks/CU by LDS; VGPR target
// 128 (r12 measured exactly 128 with same register content) -> 16
// waves/CU allowed. Catalog T3 minimum-2-phase books (m230-proven):
//   per tile t (buf = t&1):
//     [advance W base if t==63 && !fin]
//     stage(t+1) -> buf^1          (4 gl16; overwrites buf of t-1,
//                                   safe: t-1 reads done before t-1's
//                                   end barrier)
//     phased frag reads + 32 MFMA  (VGPR-phased as r12: A0-3+B, A4-7)
//     VMW(0)                       (drains stage(t+1); covered by the
//                                   reads+MFMA above + co-resident block)
//     BARRIER                      (1 barrier/tile)
//   prologue: stage(0); VMW(0); BARRIER.  Tail: last tile stages nothing.
// Persistent grid=512 (2/CU): mt=(c<<4)+(j&15) fixed (A shared 4-way
// among 64 blocks/XCD; 16 MB/XCD ~ L3); nt=4*sg+(j>>4), NSEG=11
// (4 x 1MB W panels concurrent per XCD).
// =====================================================================
__global__ __launch_bounds__(512, 2)
void k_moe1(const bf16* __restrict__ xb, const bf16* __restrict__ w1b,
            const bf16* __restrict__ w3b, const int* __restrict__ counts,
            bf16* __restrict__ h) {
    extern __shared__ __align__(16) char sm[];
    const int tid = threadIdx.x;
    const int c = blockIdx.x & 7;      // XCD (round-robin dispatch, 512%8==0)
    const int j = blockIdx.x >> 3;     // [0,64)
    const int NSEG = 11;

    const int mt = (c << 4) + (j & 15);
    const int row0 = mt * 256;
    const int e = expert_of(counts, row0);

    const int s0 = swz(tid * 16);
    const int s1 = 8192 + s0;
    const int dst0 = tid * 16;

    const char* sa0 = (const char*)xb + (((size_t)(row0 + (s0 >> 6)) * DD) << 1) + (s0 & 63);
    const char* sa1 = (const char*)xb + (((size_t)(row0 + (s1 >> 6)) * DD) << 1) + (s1 & 63);
    const char* w1p = (const char*)(w1b + (size_t)e * HH * DD);
    const char* w3p = (const char*)(w3b + (size_t)e * HH * DD);
    int c0 = (j >> 4) * 128;           // seg-0 weight col block (nt = 4*sg + (j>>4))
    const char* sa2 = w1p + (((size_t)(c0 + (s0 >> 6)) * DD) << 1) + (s0 & 63);
    const char* sa3 = w3p + (((size_t)(c0 + (s0 >> 6)) * DD) << 1) + (s0 & 63);
    const size_t WADV = ((size_t)512 * DD) << 1;   // nt += 4 per segment

    auto stageA = [&](int ko, int bufb) {
        gl16(sa0 + ko, sm + bufb + dst0);
        gl16(sa1 + ko, sm + bufb + 8192 + dst0);
    };
    auto stageB = [&](int ko, int bufb) {
        gl16(sa2 + ko, sm + bufb + 16384 + dst0);
        gl16(sa3 + ko, sm + bufb + 24576 + dst0);
    };

    const int lane = tid & 63, wv = tid >> 6;
    const int wrow = wv >> 2, wcol = wv & 3;      // wave = 128 rows x 32 cols/mat
    const int lrow = lane & 15, kb = (lane >> 4) << 4;
    const int aoff0 = swz((wrow * 128 + lrow) * 64 + kb);   // + mi*1024
    const int boff0 = swz((wcol * 32 + lrow) * 64 + kb);    // + ni*1024

    f32x4 acc1[8][2] = {};
    f32x4 acc3[8][2] = {};

    // prologue: tile 0 -> buf 0, full drain
    stageA(0, 0); stageB(0, 0);
    VMW(0);
    BARRIER();

    int ccol0 = (j >> 4) * 128;
    const int crow = row0 + wrow * 128 + ((lane >> 4) << 2);

    for (int sg = 0; sg < NSEG; ++sg) {
        const bool fin = (sg == NSEG - 1);
        for (int tp = 0; tp < 32; ++tp) {
#pragma unroll
            for (int kk = 0; kk < 2; ++kk) {
                const int t = tp * 2 + kk;
                const char* db = sm + (kk << 15);            // buf t&1 (compile-time)
                const int bS = ((kk + 1) & 1) << 15;         // buf (t+1)&1
                const bool dostage = !(fin && t == 63);
                if (t == 63 && !fin) { sa2 += WADV; sa3 += WADV; }   // next-seg cols
                if (dostage) {
                    const int ko1 = ((t + 1) & 63) << 6;
                    stageA(ko1, bS);
                    stageB(ko1, bS);
                }
                // ---- phased frag reads + MFMA (VGPR-bounded as r12) ----
                bf16x8 af[4], b1[2], b3[2];
#pragma unroll
                for (int mi = 0; mi < 4; ++mi) af[mi] = *(const bf16x8*)(db + aoff0 + mi * 1024);
#pragma unroll
                for (int ni = 0; ni < 2; ++ni) {
                    b1[ni] = *(const bf16x8*)(db + 16384 + boff0 + ni * 1024);
                    b3[ni] = *(const bf16x8*)(db + 24576 + boff0 + ni * 1024);
                }
                LGKM0();
                __builtin_amdgcn_s_setprio(1);
#pragma unroll
                for (int mi = 0; mi < 4; ++mi)
#pragma unroll
                    for (int ni = 0; ni < 2; ++ni) {
                        acc1[mi][ni] = __builtin_amdgcn_mfma_f32_16x16x32_bf16(af[mi], b1[ni], acc1[mi][ni], 0, 0, 0);
                        acc3[mi][ni] = __builtin_amdgcn_mfma_f32_16x16x32_bf16(af[mi], b3[ni], acc3[mi][ni], 0, 0, 0);
                    }
                __builtin_amdgcn_s_setprio(0);
                bf16x8 ag[4];
#pragma unroll
                for (int mi = 0; mi < 4; ++mi) ag[mi] = *(const bf16x8*)(db + aoff0 + (mi + 4) * 1024);
                LGKM0();
                __builtin_amdgcn_s_setprio(1);
#pragma unroll
                for (int mi = 0; mi < 4; ++mi)
#pragma unroll
                    for (int ni = 0; ni < 2; ++ni) {
                        acc1[mi + 4][ni] = __builtin_amdgcn_mfma_f32_16x16x32_bf16(ag[mi], b1[ni], acc1[mi + 4][ni], 0, 0, 0);
                        acc3[mi + 4][ni] = __builtin_amdgcn_mfma_f32_16x16x32_bf16(ag[mi], b3[ni], acc3[mi + 4][ni], 0, 0, 0);
                    }
                __builtin_amdgcn_s_setprio(0);
                if (dostage) VMW(0);     // stage(t+1) landed; covered by compute
                BARRIER();               // single barrier per tile
            }
        }
        // segment epilogue: bf16-round h1,h3 (ragged_dot bf16 outs), silu, bf16 h
#pragma unroll
        for (int mi = 0; mi < 8; ++mi)
#pragma unroll
            for (int ni = 0; ni < 2; ++ni) {
#pragma unroll
                for (int jj = 0; jj < 4; ++jj) {
                    int row = crow + mi * 16 + jj;
                    int col = ccol0 + wcol * 32 + ni * 16 + lrow;
                    float f1 = (float)(bf16)acc1[mi][ni][jj];
                    float f3 = (float)(bf16)acc3[mi][ni][jj];
                    float s = f1 / (1.0f + __expf(-f1));
                    h[(size_t)row * HH + col] = (bf16)(s * f3);
                }
                acc1[mi][ni] = (f32x4){0.f, 0.f, 0.f, 0.f};
                acc3[mi][ni] = (f32x4){0.f, 0.f, 0.f, 0.f};
            }
        ccol0 += 512;   // nt += 4
    }
}

// =====================================================================
// r12 g2 (verbatim, proven): persistent, static inner pipeline, bf16 W2.
// =====================================================================
__global__ __launch_bounds__(512, 2)
void k_g2(const bf16* __restrict__ hb, const bf16* __restrict__ w2b,
          const int* __restrict__ counts, float* __restrict__ out) {
    extern __shared__ __align__(16) char sm[];
    const int tid = threadIdx.x;
    const int c = blockIdx.x & 7;
    const int j = blockIdx.x >> 3;     // [0,32)
    const int NSEG = 4;
    const int NT = 176;                // HH/32

    const int mt = (c << 4) + (j & 15);
    const int row0 = mt * 256;
    const int e = expert_of(counts, row0);

    const int s0 = swz(tid * 16);
    const int s1 = 8192 + s0;
    const int dst0 = tid * 16;

    const char* sa0 = (const char*)hb + (((size_t)(row0 + (s0 >> 6)) * HH) << 1) + (s0 & 63);
    const char* sa1 = (const char*)hb + (((size_t)(row0 + (s1 >> 6)) * HH) << 1) + (s1 & 63);
    const char* wp = (const char*)(w2b + (size_t)e * DD * HH);
    int c0 = (j >> 4) * 256;
    const char* sa2 = wp + (((size_t)(c0 + (s0 >> 6)) * HH) << 1) + (s0 & 63);
    const char* sa3 = wp + (((size_t)(c0 + (s1 >> 6)) * HH) << 1) + (s1 & 63);
    const size_t WADV = ((size_t)512 * HH) << 1;

    auto stageA = [&](int ko, int bufb) {
        gl16(sa0 + ko, sm + bufb + dst0);
        gl16(sa1 + ko, sm + bufb + 8192 + dst0);
    };
    auto stageB = [&](int ko, int bufb) {
        gl16(sa2 + ko, sm + bufb + 16384 + dst0);
        gl16(sa3 + ko, sm + bufb + 24576 + dst0);
    };

    const int lane = tid & 63, wv = tid >> 6;
    const int wrow = wv >> 2, wcol = wv & 3;
    const int lrow = lane & 15, kb = (lane >> 4) << 4;
    const int aoff0 = swz((wrow * 128 + lrow) * 64 + kb);
    const int boff0 = swz((wcol * 64 + lrow) * 64 + kb);

    f32x4 acc[8][4] = {};

    stageA(0, 0);          stageB(0, 0);
    stageA(64, 1 << 15);   stageB(64, 1 << 15);
    stageA(128, 2 << 15);  stageB(128, 2 << 15);
    VMW(8);
    BARRIER();

    int ccol0 = (j >> 4) * 256;
    const int crow = row0 + wrow * 128 + ((lane >> 4) << 2);

    for (int sg = 0; sg < NSEG; ++sg) {
        const bool fin = (sg == NSEG - 1);
        for (int tp = 0; tp < 44; ++tp) {
#pragma unroll
            for (int k = 0; k < 4; ++k) {
                const int t = tp * 4 + k;
                const char* db = sm + (k << 15);
                const int bS = ((k + 3) & 3) << 15;
                const int t3 = (t + 3 >= NT) ? t + 3 - NT : t + 3;
                const int ko3 = t3 << 6;
                bf16x8 af[4], bf[4];
#pragma unroll
                for (int mi = 0; mi < 4; ++mi) af[mi] = *(const bf16x8*)(db + aoff0 + mi * 1024);
#pragma unroll
                for (int ni = 0; ni < 4; ++ni) bf[ni] = *(const bf16x8*)(db + 16384 + boff0 + ni * 1024);
                if (t == NT - 3 && !fin) { sa2 += WADV; sa3 += WADV; }
                if (!fin || t < NT - 3) stageA(ko3, bS);
                BARRIER();
                LGKM0();
                __builtin_amdgcn_s_setprio(1);
#pragma unroll
                for (int mi = 0; mi < 4; ++mi)
#pragma unroll
                    for (int ni = 0; ni < 4; ++ni)
                        acc[mi][ni] = __builtin_amdgcn_mfma_f32_16x16x32_bf16(af[mi], bf[ni], acc[mi][ni], 0, 0, 0);
                __builtin_amdgcn_s_setprio(0);
                BARRIER();
                bf16x8 ag[4];
#pragma unroll
                for (int mi = 0; mi < 4; ++mi) ag[mi] = *(const bf16x8*)(db + aoff0 + (mi + 4) * 1024);
                if (!fin || t < NT - 3) { stageB(ko3, bS); VMW(8); }
                else if (t == NT - 3) { VMW(4); }
                else if (t == NT - 2) { VMW(0); }
                BARRIER();
                LGKM0();
                __builtin_amdgcn_s_setprio(1);
#pragma unroll
                for (int mi = 0; mi < 4; ++mi)
#pragma unroll
                    for (int ni = 0; ni < 4; ++ni)
                        acc[mi + 4][ni] = __builtin_amdgcn_mfma_f32_16x16x32_bf16(ag[mi], bf[ni], acc[mi + 4][ni], 0, 0, 0);
                __builtin_amdgcn_s_setprio(0);
                BARRIER();
            }
        }
#pragma unroll
        for (int mi = 0; mi < 8; ++mi)
#pragma unroll
            for (int ni = 0; ni < 4; ++ni) {
#pragma unroll
                for (int jj = 0; jj < 4; ++jj) {
                    int row = crow + mi * 16 + jj;
                    int col = ccol0 + wcol * 64 + ni * 16 + lrow;
                    out[(size_t)row * DD + col] = (float)(bf16)acc[mi][ni][jj];
                }
                acc[mi][ni] = (f32x4){0.f, 0.f, 0.f, 0.f};
            }
        ccol0 += 512;
    }
}

extern "C" void kernel_launch(void* const* d_in, const int* in_sizes, int n_in,
                              void* d_out, int out_size, void* d_ws, size_t ws_size,
                              hipStream_t stream) {
    const float* x      = (const float*)d_in[0];
    const float* w1     = (const float*)d_in[1];
    const float* w2     = (const float*)d_in[2];
    const float* w3     = (const float*)d_in[3];
    const int*   counts = (const int*)d_in[4];
    float* out = (float*)d_out;

    const size_t xb_b = (size_t)TT * DD * 2;        // 128 MiB
    const size_t h_b  = (size_t)TT * HH * 2;        // 352 MiB
    const size_t w_b  = (size_t)NE * HH * DD * 2;   // 176 MiB each
    const size_t need_full = xb_b + h_b + 2 * w_b;  // 832 MiB (proven available)
    if (ws_size < need_full) return;

    bf16* xb  = (bf16*)d_ws;
    bf16* h   = (bf16*)((char*)d_ws + xb_b);
    bf16* wsA = (bf16*)((char*)d_ws + xb_b + h_b);
    bf16* wsB = (bf16*)((char*)d_ws + xb_b + h_b + w_b);

    hipFuncSetAttribute((const void*)k_moe1, hipFuncAttributeMaxDynamicSharedMemorySize, 65536);
    hipFuncSetAttribute((const void*)k_g2,   hipFuncAttributeMaxDynamicSharedMemorySize, 131072);

    k_cvt<<<2048, 256, 0, stream>>>(x,  xb,  (long)TT * DD);
    k_cvt<<<2048, 256, 0, stream>>>(w1, wsA, (long)NE * HH * DD);
    k_cvt<<<2048, 256, 0, stream>>>(w3, wsB, (long)NE * HH * DD);
    k_moe1<<<512, 512, 65536, stream>>>(xb, wsA, wsB, counts, h);
    k_cvt<<<2048, 256, 0, stream>>>(w2, wsA, (long)NE * DD * HH);   // reuse slot A
    k_g2<<<256, 512, 131072, stream>>>(h, wsA, counts, out);
}

// Round 15
// 2648.659 us; speedup vs baseline: 1.2379x; 1.0130x over previous
//
#include <hip/hip_runtime.h>
#include <hip/hip_bf16.h>
#include <stdint.h>

// Problem constants (fixed by the reference)
#define TT 32768   // total tokens
#define DD 2048    // model dim
#define HH 5632    // hidden dim
#define NE 8       // experts

typedef __bf16 bf16;
typedef __bf16 bf16x8 __attribute__((ext_vector_type(8)));
typedef float  f32x4  __attribute__((ext_vector_type(4)));

__device__ __forceinline__ void gl16(const void* g, void* l) {
    __builtin_amdgcn_global_load_lds(
        (const __attribute__((address_space(1))) void*)g,
        (__attribute__((address_space(3))) void*)l, 16, 0, 0);
}
#define VMW(n) asm volatile("s_waitcnt vmcnt(" #n ")" ::: "memory")
#define LGKM0() do { asm volatile("s_waitcnt lgkmcnt(0)" ::: "memory"); \
                     __builtin_amdgcn_sched_barrier(0); } while (0)
#define BARRIER() __builtin_amdgcn_s_barrier()

// LDS XOR-swizzle for 64-B rows: measured 0 bank conflicts (r2-r14).
__device__ __forceinline__ int swz(int off) { return off ^ (((off >> 7) & 3) << 4); }

__device__ __forceinline__ int expert_of(const int* counts, int row0) {
    int base = 0;
    for (int i = 0; i < NE; ++i) { int c = counts[i]; if (row0 < base + c) return i; base += c; }
    return NE - 1;
}

// ---------------- f32 -> bf16 convert, generic ----------------
__device__ __forceinline__ void cvt_range(const float* __restrict__ in,
                                          bf16* __restrict__ out, long n) {
    long i = ((long)blockIdx.x * 256 + threadIdx.x) * 8;
    const long stride = (long)gridDim.x * 256 * 8;
    for (; i < n; i += stride) {
        const float4* p = (const float4*)(in + i);
        float4 a = p[0], b = p[1];
        union { bf16 v[8]; uint4 u; } r;
        r.v[0] = (bf16)a.x; r.v[1] = (bf16)a.y; r.v[2] = (bf16)a.z; r.v[3] = (bf16)a.w;
        r.v[4] = (bf16)b.x; r.v[5] = (bf16)b.y; r.v[6] = (bf16)b.z; r.v[7] = (bf16)b.w;
        *(uint4*)(out + i) = r.u;
    }
}

__global__ __launch_bounds__(256)
void k_cvt(const float* __restrict__ in, bf16* __restrict__ out, long n) {
    cvt_range(in, out, n);
}

// one launch for x, w1, w3 (saves 2 launch gaps; all BW-bound)
__global__ __launch_bounds__(256)
void k_cvt3(const float* __restrict__ x,  bf16* __restrict__ xb,
            const float* __restrict__ w1, bf16* __restrict__ w1b,
            const float* __restrict__ w3, bf16* __restrict__ w3b) {
    cvt_range(x,  xb,  (long)TT * DD);
    cvt_range(w1, w1b, (long)NE * HH * DD);
    cvt_range(w3, w3b, (long)NE * HH * DD);
}

// =====================================================================
// r15 moe1 = r12 proven kernel + FUSED w2 f32->bf16 convert trickle.
// Cvt placement is overdrain-safe: the 2 cvt VMEM ops (per 4th tile)
// are issued AFTER that tile's VMW and only make later VMW(8)s
// stricter (extra queue entries) — required stage drains still happen;
// no ledger change.  w2 slices: block b, group g=sg*16+tp (352/block),
// 1024 f32/group = 512 thr x float2.  g2 reads w2b after moe1 ends.
// Everything else identical to r12 (best measured: 2582 us).
// =====================================================================
__global__ __launch_bounds__(512, 2)
void k_moe1(const bf16* __restrict__ xb, const bf16* __restrict__ w1b,
            const bf16* __restrict__ w3b, const int* __restrict__ counts,
            bf16* __restrict__ h,
            const float* __restrict__ w2f, bf16* __restrict__ w2o) {
    extern __shared__ __align__(16) char sm[];
    const int tid = threadIdx.x;
    const int c = blockIdx.x & 7;      // XCD (round-robin dispatch, 256%8==0)
    const int j = blockIdx.x >> 3;     // [0,32)
    const int NSEG = 22;

    const int mt = (c << 4) + (j & 15);
    const int row0 = mt * 256;
    const int e = expert_of(counts, row0);

    const int s0 = swz(tid * 16);
    const int s1 = 8192 + s0;
    const int dst0 = tid * 16;

    const char* sa0 = (const char*)xb + (((size_t)(row0 + (s0 >> 6)) * DD) << 1) + (s0 & 63);
    const char* sa1 = (const char*)xb + (((size_t)(row0 + (s1 >> 6)) * DD) << 1) + (s1 & 63);
    const char* w1p = (const char*)(w1b + (size_t)e * HH * DD);
    const char* w3p = (const char*)(w3b + (size_t)e * HH * DD);
    int c0 = (j >> 4) * 128;           // seg-0 weight col block (nt = sg*2 + j>>4)
    const char* sa2 = w1p + (((size_t)(c0 + (s0 >> 6)) * DD) << 1) + (s0 & 63);
    const char* sa3 = w3p + (((size_t)(c0 + (s0 >> 6)) * DD) << 1) + (s0 & 63);
    const size_t WADV = ((size_t)256 * DD) << 1;   // nt += 2 per segment

    // fused w2-cvt bases (per-block slice: 352 groups x 1024 f32)
    const size_t gbase = (size_t)blockIdx.x * 352;
    const bool docvt = (w2f != nullptr);

    auto stageA = [&](int ko, int bufb) {
        gl16(sa0 + ko, sm + bufb + dst0);
        gl16(sa1 + ko, sm + bufb + 8192 + dst0);
    };
    auto stageB = [&](int ko, int bufb) {
        gl16(sa2 + ko, sm + bufb + 16384 + dst0);
        gl16(sa3 + ko, sm + bufb + 24576 + dst0);
    };

    const int lane = tid & 63, wv = tid >> 6;
    const int wrow = wv >> 2, wcol = wv & 3;      // wave = 128 rows x 32 cols/mat
    const int lrow = lane & 15, kb = (lane >> 4) << 4;
    const int aoff0 = swz((wrow * 128 + lrow) * 64 + kb);   // + mi*1024
    const int boff0 = swz((wcol * 32 + lrow) * 64 + kb);    // + ni*1024

    f32x4 acc1[8][2] = {};
    f32x4 acc3[8][2] = {};

    // prologue: tiles 0,1,2 -> bufs 0,1,2 (12 loads); VMW(8) drains tile 0
    stageA(0, 0);          stageB(0, 0);
    stageA(64, 1 << 15);   stageB(64, 1 << 15);
    stageA(128, 2 << 15);  stageB(128, 2 << 15);
    VMW(8);
    BARRIER();

    int ccol0 = (j >> 4) * 128;
    const int crow = row0 + wrow * 128 + ((lane >> 4) << 2);

    for (int sg = 0; sg < NSEG; ++sg) {
        const bool fin = (sg == NSEG - 1);
        for (int tp = 0; tp < 16; ++tp) {
#pragma unroll
            for (int k = 0; k < 4; ++k) {
                const int t = tp * 4 + k;
                const char* db = sm + (k << 15);             // compile-time
                const int bS = ((k + 3) & 3) << 15;          // compile-time
                const int ko3 = ((t + 3) & 63) << 6;
                bf16x8 af[4], b1[2], b3[2];
                // ---------------- phase A: mi 0-3 ----------------
#pragma unroll
                for (int mi = 0; mi < 4; ++mi) af[mi] = *(const bf16x8*)(db + aoff0 + mi * 1024);
#pragma unroll
                for (int ni = 0; ni < 2; ++ni) {
                    b1[ni] = *(const bf16x8*)(db + 16384 + boff0 + ni * 1024);
                    b3[ni] = *(const bf16x8*)(db + 24576 + boff0 + ni * 1024);
                }
                if (t == 61 && !fin) { sa2 += WADV; sa3 += WADV; }   // next-seg W cols
                if (!fin || t < 61) stageA(ko3, bS);
                BARRIER();
                LGKM0();
                __builtin_amdgcn_s_setprio(1);
#pragma unroll
                for (int mi = 0; mi < 4; ++mi)
#pragma unroll
                    for (int ni = 0; ni < 2; ++ni) {
                        acc1[mi][ni] = __builtin_amdgcn_mfma_f32_16x16x32_bf16(af[mi], b1[ni], acc1[mi][ni], 0, 0, 0);
                        acc3[mi][ni] = __builtin_amdgcn_mfma_f32_16x16x32_bf16(af[mi], b3[ni], acc3[mi][ni], 0, 0, 0);
                    }
                __builtin_amdgcn_s_setprio(0);
                BARRIER();
                // ---------------- phase B: mi 4-7 (B frags reused) ----------------
                bf16x8 ag[4];
#pragma unroll
                for (int mi = 0; mi < 4; ++mi) ag[mi] = *(const bf16x8*)(db + aoff0 + (mi + 4) * 1024);
                if (!fin || t < 61) { stageB(ko3, bS); VMW(8); }
                else if (t == 61) { VMW(4); }
                else if (t == 62) { VMW(0); }
                BARRIER();
                LGKM0();
                __builtin_amdgcn_s_setprio(1);
#pragma unroll
                for (int mi = 0; mi < 4; ++mi)
#pragma unroll
                    for (int ni = 0; ni < 2; ++ni) {
                        acc1[mi + 4][ni] = __builtin_amdgcn_mfma_f32_16x16x32_bf16(ag[mi], b1[ni], acc1[mi + 4][ni], 0, 0, 0);
                        acc3[mi + 4][ni] = __builtin_amdgcn_mfma_f32_16x16x32_bf16(ag[mi], b3[ni], acc3[mi + 4][ni], 0, 0, 0);
                    }
                __builtin_amdgcn_s_setprio(0);
                // ---- fused w2 cvt trickle (every 4th tile; after VMW,
                //      before barrier: only stiffens later VMW(8)s) ----
                if (k == 0 && docvt) {
                    const size_t g = gbase + (size_t)sg * 16 + tp;
                    const float2 v = *(const float2*)((const char*)w2f + (g << 12) + ((size_t)tid << 3));
                    union { bf16 hv[2]; uint32_t u; } r;
                    r.hv[0] = (bf16)v.x; r.hv[1] = (bf16)v.y;
                    *(uint32_t*)((char*)w2o + (g << 11) + ((size_t)tid << 2)) = r.u;
                }
                BARRIER();
            }
        }
        // segment epilogue: bf16-round h1,h3 (ragged_dot bf16 outs), silu, bf16 h
#pragma unroll
        for (int mi = 0; mi < 8; ++mi)
#pragma unroll
            for (int ni = 0; ni < 2; ++ni) {
#pragma unroll
                for (int jj = 0; jj < 4; ++jj) {
                    int row = crow + mi * 16 + jj;
                    int col = ccol0 + wcol * 32 + ni * 16 + lrow;
                    float f1 = (float)(bf16)acc1[mi][ni][jj];
                    float f3 = (float)(bf16)acc3[mi][ni][jj];
                    float s = f1 / (1.0f + __expf(-f1));
                    h[(size_t)row * HH + col] = (bf16)(s * f3);
                }
                acc1[mi][ni] = (f32x4){0.f, 0.f, 0.f, 0.f};
                acc3[mi][ni] = (f32x4){0.f, 0.f, 0.f, 0.f};
            }
        ccol0 += 256;   // nt += 2
    }
}

// =====================================================================
// r12 g2 (verbatim, proven): persistent, static inner pipeline, bf16 W2.
// =====================================================================
__global__ __launch_bounds__(512, 2)
void k_g2(const bf16* __restrict__ hb, const bf16* __restrict__ w2b,
          const int* __restrict__ counts, float* __restrict__ out) {
    extern __shared__ __align__(16) char sm[];
    const int tid = threadIdx.x;
    const int c = blockIdx.x & 7;
    const int j = blockIdx.x >> 3;     // [0,32)
    const int NSEG = 4;
    const int NT = 176;                // HH/32

    const int mt = (c << 4) + (j & 15);
    const int row0 = mt * 256;
    const int e = expert_of(counts, row0);

    const int s0 = swz(tid * 16);
    const int s1 = 8192 + s0;
    const int dst0 = tid * 16;

    const char* sa0 = (const char*)hb + (((size_t)(row0 + (s0 >> 6)) * HH) << 1) + (s0 & 63);
    const char* sa1 = (const char*)hb + (((size_t)(row0 + (s1 >> 6)) * HH) << 1) + (s1 & 63);
    const char* wp = (const char*)(w2b + (size_t)e * DD * HH);
    int c0 = (j >> 4) * 256;
    const char* sa2 = wp + (((size_t)(c0 + (s0 >> 6)) * HH) << 1) + (s0 & 63);
    const char* sa3 = wp + (((size_t)(c0 + (s1 >> 6)) * HH) << 1) + (s1 & 63);
    const size_t WADV = ((size_t)512 * HH) << 1;

    auto stageA = [&](int ko, int bufb) {
        gl16(sa0 + ko, sm + bufb + dst0);
        gl16(sa1 + ko, sm + bufb + 8192 + dst0);
    };
    auto stageB = [&](int ko, int bufb) {
        gl16(sa2 + ko, sm + bufb + 16384 + dst0);
        gl16(sa3 + ko, sm + bufb + 24576 + dst0);
    };

    const int lane = tid & 63, wv = tid >> 6;
    const int wrow = wv >> 2, wcol = wv & 3;
    const int lrow = lane & 15, kb = (lane >> 4) << 4;
    const int aoff0 = swz((wrow * 128 + lrow) * 64 + kb);
    const int boff0 = swz((wcol * 64 + lrow) * 64 + kb);

    f32x4 acc[8][4] = {};

    stageA(0, 0);          stageB(0, 0);
    stageA(64, 1 << 15);   stageB(64, 1 << 15);
    stageA(128, 2 << 15);  stageB(128, 2 << 15);
    VMW(8);
    BARRIER();

    int ccol0 = (j >> 4) * 256;
    const int crow = row0 + wrow * 128 + ((lane >> 4) << 2);

    for (int sg = 0; sg < NSEG; ++sg) {
        const bool fin = (sg == NSEG - 1);
        for (int tp = 0; tp < 44; ++tp) {
#pragma unroll
            for (int k = 0; k < 4; ++k) {
                const int t = tp * 4 + k;
                const char* db = sm + (k << 15);
                const int bS = ((k + 3) & 3) << 15;
                const int t3 = (t + 3 >= NT) ? t + 3 - NT : t + 3;
                const int ko3 = t3 << 6;
                bf16x8 af[4], bf[4];
#pragma unroll
                for (int mi = 0; mi < 4; ++mi) af[mi] = *(const bf16x8*)(db + aoff0 + mi * 1024);
#pragma unroll
                for (int ni = 0; ni < 4; ++ni) bf[ni] = *(const bf16x8*)(db + 16384 + boff0 + ni * 1024);
                if (t == NT - 3 && !fin) { sa2 += WADV; sa3 += WADV; }
                if (!fin || t < NT - 3) stageA(ko3, bS);
                BARRIER();
                LGKM0();
                __builtin_amdgcn_s_setprio(1);
#pragma unroll
                for (int mi = 0; mi < 4; ++mi)
#pragma unroll
                    for (int ni = 0; ni < 4; ++ni)
                        acc[mi][ni] = __builtin_amdgcn_mfma_f32_16x16x32_bf16(af[mi], bf[ni], acc[mi][ni], 0, 0, 0);
                __builtin_amdgcn_s_setprio(0);
                BARRIER();
                bf16x8 ag[4];
#pragma unroll
                for (int mi = 0; mi < 4; ++mi) ag[mi] = *(const bf16x8*)(db + aoff0 + (mi + 4) * 1024);
                if (!fin || t < NT - 3) { stageB(ko3, bS); VMW(8); }
                else if (t == NT - 3) { VMW(4); }
                else if (t == NT - 2) { VMW(0); }
                BARRIER();
                LGKM0();
                __builtin_amdgcn_s_setprio(1);
#pragma unroll
                for (int mi = 0; mi < 4; ++mi)
#pragma unroll
                    for (int ni = 0; ni < 4; ++ni)
                        acc[mi + 4][ni] = __builtin_amdgcn_mfma_f32_16x16x32_bf16(ag[mi], bf[ni], acc[mi + 4][ni], 0, 0, 0);
                __builtin_amdgcn_s_setprio(0);
                BARRIER();
            }
        }
#pragma unroll
        for (int mi = 0; mi < 8; ++mi)
#pragma unroll
            for (int ni = 0; ni < 4; ++ni) {
#pragma unroll
                for (int jj = 0; jj < 4; ++jj) {
                    int row = crow + mi * 16 + jj;
                    int col = ccol0 + wcol * 64 + ni * 16 + lrow;
                    out[(size_t)row * DD + col] = (float)(bf16)acc[mi][ni][jj];
                }
                acc[mi][ni] = (f32x4){0.f, 0.f, 0.f, 0.f};
            }
        ccol0 += 512;
    }
}

extern "C" void kernel_launch(void* const* d_in, const int* in_sizes, int n_in,
                              void* d_out, int out_size, void* d_ws, size_t ws_size,
                              hipStream_t stream) {
    const float* x      = (const float*)d_in[0];
    const float* w1     = (const float*)d_in[1];
    const float* w2     = (const float*)d_in[2];
    const float* w3     = (const float*)d_in[3];
    const int*   counts = (const int*)d_in[4];
    float* out = (float*)d_out;

    const size_t xb_b = (size_t)TT * DD * 2;        // 128 MiB
    const size_t h_b  = (size_t)TT * HH * 2;        // 352 MiB
    const size_t w_b  = (size_t)NE * HH * DD * 2;   // 176 MiB each
    const size_t need_base  = xb_b + h_b + 2 * w_b; // 832 MiB (proven available)
    const size_t need_fused = xb_b + h_b + 3 * w_b; // 1008 MiB (w2 gets own slot)
    if (ws_size < need_base) return;

    bf16* xb  = (bf16*)d_ws;
    bf16* h   = (bf16*)((char*)d_ws + xb_b);
    bf16* wsA = (bf16*)((char*)d_ws + xb_b + h_b);
    bf16* wsB = (bf16*)((char*)d_ws + xb_b + h_b + w_b);

    hipFuncSetAttribute((const void*)k_moe1, hipFuncAttributeMaxDynamicSharedMemorySize, 131072);
    hipFuncSetAttribute((const void*)k_g2,   hipFuncAttributeMaxDynamicSharedMemorySize, 131072);

    if (ws_size >= need_fused) {
        bf16* w2b = (bf16*)((char*)d_ws + xb_b + h_b + 2 * w_b);
        k_cvt3<<<2048, 256, 0, stream>>>(x, xb, w1, wsA, w3, wsB);
        k_moe1<<<256, 512, 131072, stream>>>(xb, wsA, wsB, counts, h, w2, w2b);
        k_g2<<<256, 512, 131072, stream>>>(h, w2b, counts, out);
    } else {
        k_cvt3<<<2048, 256, 0, stream>>>(x, xb, w1, wsA, w3, wsB);
        k_moe1<<<256, 512, 131072, stream>>>(xb, wsA, wsB, counts, h, nullptr, nullptr);
        k_cvt<<<2048, 256, 0, stream>>>(w2, wsA, (long)NE * DD * HH);   // reuse slot A
        k_g2<<<256, 512, 131072, stream>>>(h, wsA, counts, out);
    }
}

// Round 16
// 2617.358 us; speedup vs baseline: 1.2527x; 1.0120x over previous
//
#include <hip/hip_runtime.h>
#include <hip/hip_bf16.h>
#include <stdint.h>

// Problem constants (fixed by the reference)
#define TT 32768   // total tokens
#define DD 2048    // model dim
#define HH 5632    // hidden dim
#define NE 8       // experts

typedef __bf16 bf16;
typedef __bf16 bf16x8 __attribute__((ext_vector_type(8)));
typedef float  f32x4  __attribute__((ext_vector_type(4)));

__device__ __forceinline__ void gl16(const void* g, void* l) {
    __builtin_amdgcn_global_load_lds(
        (const __attribute__((address_space(1))) void*)g,
        (__attribute__((address_space(3))) void*)l, 16, 0, 0);
}
#define VMW(n) asm volatile("s_waitcnt vmcnt(" #n ")" ::: "memory")
#define LGKM0() do { asm volatile("s_waitcnt lgkmcnt(0)" ::: "memory"); \
                     __builtin_amdgcn_sched_barrier(0); } while (0)
#define BARRIER() __builtin_amdgcn_s_barrier()

// LDS XOR-swizzle for 64-B rows: measured 0 bank conflicts (r2-r15).
__device__ __forceinline__ int swz(int off) { return off ^ (((off >> 7) & 3) << 4); }

__device__ __forceinline__ int expert_of(const int* counts, int row0) {
    int base = 0;
    for (int i = 0; i < NE; ++i) { int c = counts[i]; if (row0 < base + c) return i; base += c; }
    return NE - 1;
}

// ---------------- f32 -> bf16 convert ----------------
__device__ __forceinline__ void cvt_range(const float* __restrict__ in,
                                          bf16* __restrict__ out, long n) {
    long i = ((long)blockIdx.x * 256 + threadIdx.x) * 8;
    const long stride = (long)gridDim.x * 256 * 8;
    for (; i < n; i += stride) {
        const float4* p = (const float4*)(in + i);
        float4 a = p[0], b = p[1];
        union { bf16 v[8]; uint4 u; } r;
        r.v[0] = (bf16)a.x; r.v[1] = (bf16)a.y; r.v[2] = (bf16)a.z; r.v[3] = (bf16)a.w;
        r.v[4] = (bf16)b.x; r.v[5] = (bf16)b.y; r.v[6] = (bf16)b.z; r.v[7] = (bf16)b.w;
        *(uint4*)(out + i) = r.u;
    }
}

// all four conversions in one launch (saves launch gaps; all BW-bound)
__global__ __launch_bounds__(256)
void k_cvt4(const float* __restrict__ x,  bf16* __restrict__ xb,
            const float* __restrict__ w1, bf16* __restrict__ w1b,
            const float* __restrict__ w3, bf16* __restrict__ w3b,
            const float* __restrict__ w2, bf16* __restrict__ w2b) {
    cvt_range(x,  xb,  (long)TT * DD);
    cvt_range(w1, w1b, (long)NE * HH * DD);
    cvt_range(w3, w3b, (long)NE * HH * DD);
    if (w2b) cvt_range(w2, w2b, (long)NE * DD * HH);
}

__global__ __launch_bounds__(256)
void k_cvt(const float* __restrict__ in, bf16* __restrict__ out, long n) {
    cvt_range(in, out, n);
}

// =====================================================================
// r12 moe1 (verbatim, best measured): persistent (grid=256) + static
// inner pipeline. NBUF=4 x 32 KiB = 128 KiB; 64%4==0 -> every segment
// starts at buf 0; inner loop = 16 groups x unroll(4) -> buffer bases
// compile-time. Books = r4-proven 2-phase, stage lead 3, VMW(8) steady,
// tail VMW(4)/VMW(0) final segment only; vmcnt chain continuous across
// segment boundaries (W-bases advance at t==61).
// =====================================================================
__global__ __launch_bounds__(512, 2)
void k_moe1(const bf16* __restrict__ xb, const bf16* __restrict__ w1b,
            const bf16* __restrict__ w3b, const int* __restrict__ counts,
            bf16* __restrict__ h) {
    extern __shared__ __align__(16) char sm[];
    const int tid = threadIdx.x;
    const int c = blockIdx.x & 7;      // XCD (round-robin dispatch, 256%8==0)
    const int j = blockIdx.x >> 3;     // [0,32)
    const int NSEG = 22;

    const int mt = (c << 4) + (j & 15);
    const int row0 = mt * 256;
    const int e = expert_of(counts, row0);

    const int s0 = swz(tid * 16);
    const int s1 = 8192 + s0;
    const int dst0 = tid * 16;

    const char* sa0 = (const char*)xb + (((size_t)(row0 + (s0 >> 6)) * DD) << 1) + (s0 & 63);
    const char* sa1 = (const char*)xb + (((size_t)(row0 + (s1 >> 6)) * DD) << 1) + (s1 & 63);
    const char* w1p = (const char*)(w1b + (size_t)e * HH * DD);
    const char* w3p = (const char*)(w3b + (size_t)e * HH * DD);
    int c0 = (j >> 4) * 128;           // seg-0 weight col block (nt = sg*2 + j>>4)
    const char* sa2 = w1p + (((size_t)(c0 + (s0 >> 6)) * DD) << 1) + (s0 & 63);
    const char* sa3 = w3p + (((size_t)(c0 + (s0 >> 6)) * DD) << 1) + (s0 & 63);
    const size_t WADV = ((size_t)256 * DD) << 1;   // nt += 2 per segment

    auto stageA = [&](int ko, int bufb) {
        gl16(sa0 + ko, sm + bufb + dst0);
        gl16(sa1 + ko, sm + bufb + 8192 + dst0);
    };
    auto stageB = [&](int ko, int bufb) {
        gl16(sa2 + ko, sm + bufb + 16384 + dst0);
        gl16(sa3 + ko, sm + bufb + 24576 + dst0);
    };

    const int lane = tid & 63, wv = tid >> 6;
    const int wrow = wv >> 2, wcol = wv & 3;      // wave = 128 rows x 32 cols/mat
    const int lrow = lane & 15, kb = (lane >> 4) << 4;
    const int aoff0 = swz((wrow * 128 + lrow) * 64 + kb);   // + mi*1024
    const int boff0 = swz((wcol * 32 + lrow) * 64 + kb);    // + ni*1024

    f32x4 acc1[8][2] = {};
    f32x4 acc3[8][2] = {};

    // prologue: tiles 0,1,2 -> bufs 0,1,2 (12 loads); VMW(8) drains tile 0
    stageA(0, 0);          stageB(0, 0);
    stageA(64, 1 << 15);   stageB(64, 1 << 15);
    stageA(128, 2 << 15);  stageB(128, 2 << 15);
    VMW(8);
    BARRIER();

    int ccol0 = (j >> 4) * 128;
    const int crow = row0 + wrow * 128 + ((lane >> 4) << 2);

    for (int sg = 0; sg < NSEG; ++sg) {
        const bool fin = (sg == NSEG - 1);
        for (int tp = 0; tp < 16; ++tp) {
#pragma unroll
            for (int k = 0; k < 4; ++k) {
                const int t = tp * 4 + k;
                const char* db = sm + (k << 15);             // compile-time
                const int bS = ((k + 3) & 3) << 15;          // compile-time
                const int ko3 = ((t + 3) & 63) << 6;
                bf16x8 af[4], b1[2], b3[2];
                // ---------------- phase A: mi 0-3 ----------------
#pragma unroll
                for (int mi = 0; mi < 4; ++mi) af[mi] = *(const bf16x8*)(db + aoff0 + mi * 1024);
#pragma unroll
                for (int ni = 0; ni < 2; ++ni) {
                    b1[ni] = *(const bf16x8*)(db + 16384 + boff0 + ni * 1024);
                    b3[ni] = *(const bf16x8*)(db + 24576 + boff0 + ni * 1024);
                }
                if (t == 61 && !fin) { sa2 += WADV; sa3 += WADV; }   // next-seg W cols
                if (!fin || t < 61) stageA(ko3, bS);
                BARRIER();
                LGKM0();
                __builtin_amdgcn_s_setprio(1);
#pragma unroll
                for (int mi = 0; mi < 4; ++mi)
#pragma unroll
                    for (int ni = 0; ni < 2; ++ni) {
                        acc1[mi][ni] = __builtin_amdgcn_mfma_f32_16x16x32_bf16(af[mi], b1[ni], acc1[mi][ni], 0, 0, 0);
                        acc3[mi][ni] = __builtin_amdgcn_mfma_f32_16x16x32_bf16(af[mi], b3[ni], acc3[mi][ni], 0, 0, 0);
                    }
                __builtin_amdgcn_s_setprio(0);
                BARRIER();
                // ---------------- phase B: mi 4-7 (B frags reused) ----------------
                bf16x8 ag[4];
#pragma unroll
                for (int mi = 0; mi < 4; ++mi) ag[mi] = *(const bf16x8*)(db + aoff0 + (mi + 4) * 1024);
                if (!fin || t < 61) { stageB(ko3, bS); VMW(8); }
                else if (t == 61) { VMW(4); }
                else if (t == 62) { VMW(0); }
                BARRIER();
                LGKM0();
                __builtin_amdgcn_s_setprio(1);
#pragma unroll
                for (int mi = 0; mi < 4; ++mi)
#pragma unroll
                    for (int ni = 0; ni < 2; ++ni) {
                        acc1[mi + 4][ni] = __builtin_amdgcn_mfma_f32_16x16x32_bf16(ag[mi], b1[ni], acc1[mi + 4][ni], 0, 0, 0);
                        acc3[mi + 4][ni] = __builtin_amdgcn_mfma_f32_16x16x32_bf16(ag[mi], b3[ni], acc3[mi + 4][ni], 0, 0, 0);
                    }
                __builtin_amdgcn_s_setprio(0);
                BARRIER();
            }
        }
        // segment epilogue: bf16-round h1,h3 (ragged_dot bf16 outs), silu, bf16 h
#pragma unroll
        for (int mi = 0; mi < 8; ++mi)
#pragma unroll
            for (int ni = 0; ni < 2; ++ni) {
#pragma unroll
                for (int jj = 0; jj < 4; ++jj) {
                    int row = crow + mi * 16 + jj;
                    int col = ccol0 + wcol * 32 + ni * 16 + lrow;
                    float f1 = (float)(bf16)acc1[mi][ni][jj];
                    float f3 = (float)(bf16)acc3[mi][ni][jj];
                    float s = f1 / (1.0f + __expf(-f1));
                    h[(size_t)row * HH + col] = (bf16)(s * f3);
                }
                acc1[mi][ni] = (f32x4){0.f, 0.f, 0.f, 0.f};
                acc3[mi][ni] = (f32x4){0.f, 0.f, 0.f, 0.f};
            }
        ccol0 += 256;   // nt += 2
    }
}

// =====================================================================
// r12 g2 (verbatim, proven): persistent, static inner pipeline, bf16 W2.
// =====================================================================
__global__ __launch_bounds__(512, 2)
void k_g2(const bf16* __restrict__ hb, const bf16* __restrict__ w2b,
          const int* __restrict__ counts, float* __restrict__ out) {
    extern __shared__ __align__(16) char sm[];
    const int tid = threadIdx.x;
    const int c = blockIdx.x & 7;
    const int j = blockIdx.x >> 3;     // [0,32)
    const int NSEG = 4;
    const int NT = 176;                // HH/32

    const int mt = (c << 4) + (j & 15);
    const int row0 = mt * 256;
    const int e = expert_of(counts, row0);

    const int s0 = swz(tid * 16);
    const int s1 = 8192 + s0;
    const int dst0 = tid * 16;

    const char* sa0 = (const char*)hb + (((size_t)(row0 + (s0 >> 6)) * HH) << 1) + (s0 & 63);
    const char* sa1 = (const char*)hb + (((size_t)(row0 + (s1 >> 6)) * HH) << 1) + (s1 & 63);
    const char* wp = (const char*)(w2b + (size_t)e * DD * HH);
    int c0 = (j >> 4) * 256;
    const char* sa2 = wp + (((size_t)(c0 + (s0 >> 6)) * HH) << 1) + (s0 & 63);
    const char* sa3 = wp + (((size_t)(c0 + (s1 >> 6)) * HH) << 1) + (s1 & 63);
    const size_t WADV = ((size_t)512 * HH) << 1;

    auto stageA = [&](int ko, int bufb) {
        gl16(sa0 + ko, sm + bufb + dst0);
        gl16(sa1 + ko, sm + bufb + 8192 + dst0);
    };
    auto stageB = [&](int ko, int bufb) {
        gl16(sa2 + ko, sm + bufb + 16384 + dst0);
        gl16(sa3 + ko, sm + bufb + 24576 + dst0);
    };

    const int lane = tid & 63, wv = tid >> 6;
    const int wrow = wv >> 2, wcol = wv & 3;
    const int lrow = lane & 15, kb = (lane >> 4) << 4;
    const int aoff0 = swz((wrow * 128 + lrow) * 64 + kb);
    const int boff0 = swz((wcol * 64 + lrow) * 64 + kb);

    f32x4 acc[8][4] = {};

    stageA(0, 0);          stageB(0, 0);
    stageA(64, 1 << 15);   stageB(64, 1 << 15);
    stageA(128, 2 << 15);  stageB(128, 2 << 15);
    VMW(8);
    BARRIER();

    int ccol0 = (j >> 4) * 256;
    const int crow = row0 + wrow * 128 + ((lane >> 4) << 2);

    for (int sg = 0; sg < NSEG; ++sg) {
        const bool fin = (sg == NSEG - 1);
        for (int tp = 0; tp < 44; ++tp) {
#pragma unroll
            for (int k = 0; k < 4; ++k) {
                const int t = tp * 4 + k;
                const char* db = sm + (k << 15);
                const int bS = ((k + 3) & 3) << 15;
                const int t3 = (t + 3 >= NT) ? t + 3 - NT : t + 3;
                const int ko3 = t3 << 6;
                bf16x8 af[4], bf[4];
#pragma unroll
                for (int mi = 0; mi < 4; ++mi) af[mi] = *(const bf16x8*)(db + aoff0 + mi * 1024);
#pragma unroll
                for (int ni = 0; ni < 4; ++ni) bf[ni] = *(const bf16x8*)(db + 16384 + boff0 + ni * 1024);
                if (t == NT - 3 && !fin) { sa2 += WADV; sa3 += WADV; }
                if (!fin || t < NT - 3) stageA(ko3, bS);
                BARRIER();
                LGKM0();
                __builtin_amdgcn_s_setprio(1);
#pragma unroll
                for (int mi = 0; mi < 4; ++mi)
#pragma unroll
                    for (int ni = 0; ni < 4; ++ni)
                        acc[mi][ni] = __builtin_amdgcn_mfma_f32_16x16x32_bf16(af[mi], bf[ni], acc[mi][ni], 0, 0, 0);
                __builtin_amdgcn_s_setprio(0);
                BARRIER();
                bf16x8 ag[4];
#pragma unroll
                for (int mi = 0; mi < 4; ++mi) ag[mi] = *(const bf16x8*)(db + aoff0 + (mi + 4) * 1024);
                if (!fin || t < NT - 3) { stageB(ko3, bS); VMW(8); }
                else if (t == NT - 3) { VMW(4); }
                else if (t == NT - 2) { VMW(0); }
                BARRIER();
                LGKM0();
                __builtin_amdgcn_s_setprio(1);
#pragma unroll
                for (int mi = 0; mi < 4; ++mi)
#pragma unroll
                    for (int ni = 0; ni < 4; ++ni)
                        acc[mi + 4][ni] = __builtin_amdgcn_mfma_f32_16x16x32_bf16(ag[mi], bf[ni], acc[mi + 4][ni], 0, 0, 0);
                __builtin_amdgcn_s_setprio(0);
                BARRIER();
            }
        }
#pragma unroll
        for (int mi = 0; mi < 8; ++mi)
#pragma unroll
            for (int ni = 0; ni < 4; ++ni) {
#pragma unroll
                for (int jj = 0; jj < 4; ++jj) {
                    int row = crow + mi * 16 + jj;
                    int col = ccol0 + wcol * 64 + ni * 16 + lrow;
                    out[(size_t)row * DD + col] = (float)(bf16)acc[mi][ni][jj];
                }
                acc[mi][ni] = (f32x4){0.f, 0.f, 0.f, 0.f};
            }
        ccol0 += 512;
    }
}

extern "C" void kernel_launch(void* const* d_in, const int* in_sizes, int n_in,
                              void* d_out, int out_size, void* d_ws, size_t ws_size,
                              hipStream_t stream) {
    const float* x      = (const float*)d_in[0];
    const float* w1     = (const float*)d_in[1];
    const float* w2     = (const float*)d_in[2];
    const float* w3     = (const float*)d_in[3];
    const int*   counts = (const int*)d_in[4];
    float* out = (float*)d_out;

    const size_t xb_b = (size_t)TT * DD * 2;        // 128 MiB
    const size_t h_b  = (size_t)TT * HH * 2;        // 352 MiB
    const size_t w_b  = (size_t)NE * HH * DD * 2;   // 176 MiB each
    const size_t need_base  = xb_b + h_b + 2 * w_b; // 832 MiB (proven available)
    const size_t need_w2own = xb_b + h_b + 3 * w_b; // 1008 MiB (w2 own slot)
    if (ws_size < need_base) return;

    bf16* xb  = (bf16*)d_ws;
    bf16* h   = (bf16*)((char*)d_ws + xb_b);
    bf16* wsA = (bf16*)((char*)d_ws + xb_b + h_b);
    bf16* wsB = (bf16*)((char*)d_ws + xb_b + h_b + w_b);

    hipFuncSetAttribute((const void*)k_moe1, hipFuncAttributeMaxDynamicSharedMemorySize, 131072);
    hipFuncSetAttribute((const void*)k_g2,   hipFuncAttributeMaxDynamicSharedMemorySize, 131072);

    if (ws_size >= need_w2own) {
        // all 4 converts in one upfront launch; w2b has its own slot
        bf16* w2b = (bf16*)((char*)d_ws + xb_b + h_b + 2 * w_b);
        k_cvt4<<<2048, 256, 0, stream>>>(x, xb, w1, wsA, w3, wsB, w2, w2b);
        k_moe1<<<256, 512, 131072, stream>>>(xb, wsA, wsB, counts, h);
        k_g2<<<256, 512, 131072, stream>>>(h, w2b, counts, out);
    } else {
        // r12 path: w2 converted into slot A after moe1 no longer needs it
        k_cvt4<<<2048, 256, 0, stream>>>(x, xb, w1, wsA, w3, wsB, nullptr, nullptr);
        k_moe1<<<256, 512, 131072, stream>>>(xb, wsA, wsB, counts, h);
        k_cvt<<<2048, 256, 0, stream>>>(w2, wsA, (long)NE * DD * HH);
        k_g2<<<256, 512, 131072, stream>>>(h, wsA, counts, out);
    }
}